// Round 9
// baseline (62.604 us; speedup 1.0000x reference)
//
#include <hip/hip_runtime.h>
#include <math.h>

#define THR_BASE 9.42477e-5f  // sin(3e-4 * pi/10): proven margin (rounds 2-8)

// Predicated (border) halo row load
#define LOADROW_P(DST, RR)                                                \
    {                                                                     \
        int rr = (RR);                                                    \
        bool rok = (rr >= 0) && (rr < 512);                               \
        const float* rp = img + (size_t)(rok ? rr : row) * 512;           \
        const float4* rp4 = (const float4*)(rp + col0);                   \
        float4 v0 = rp4[0], v1 = rp4[1];                                  \
        float lf = rp[(cw > 0) ? (col0 - 1) : col0];                      \
        float rt = rp[(cw < 63) ? (col0 + 8) : col0];                     \
        float m = rok ? 1.0f : 0.0f;                                      \
        DST[0] = (cw > 0 && rok) ? lf : 0.0f;                             \
        DST[1] = v0.x * m; DST[2] = v0.y * m;                             \
        DST[3] = v0.z * m; DST[4] = v0.w * m;                             \
        DST[5] = v1.x * m; DST[6] = v1.y * m;                             \
        DST[7] = v1.z * m; DST[8] = v1.w * m;                             \
        DST[9] = (cw < 63 && rok) ? rt : 0.0f;                            \
    }

// Unpredicated (interior-wave) halo row load
#define LOADROW_F(DST, RR)                                                \
    {                                                                     \
        const float* rp = img + (size_t)(RR) * 512;                       \
        const float4* rp4 = (const float4*)(rp + col0);                   \
        float4 v0 = rp4[0], v1 = rp4[1];                                  \
        DST[0] = rp[col0 - 1];                                            \
        DST[1] = v0.x; DST[2] = v0.y; DST[3] = v0.z; DST[4] = v0.w;       \
        DST[5] = v1.x; DST[6] = v1.y; DST[7] = v1.z; DST[8] = v1.w;       \
        DST[9] = rp[col0 + 8];                                            \
    }

// ---------------- Kernel A: hot path, no f64, no fixup code ----------------
// x: (16,1,512,512) f32 ; out: (16,10,64,64) f32
// thread t -> (n, ch, cw, r): r = t & 7. Boundary pixels -> record list.
__global__ void __launch_bounds__(256, 8) hog_main(const float* __restrict__ x,
                                                   float* __restrict__ out,
                                                   unsigned* __restrict__ cnt,
                                                   unsigned* __restrict__ rec,
                                                   unsigned cap) {
    int t    = blockIdx.x * 256 + threadIdx.x;
    int r    = t & 7;
    int cell = t >> 3;           // 0 .. 65535
    int cw   = cell & 63;
    int ch   = (cell >> 6) & 63;
    int n    = cell >> 12;

    const float* img = x + (size_t)n * (512 * 512);
    int row  = ch * 8 + r;
    int col0 = cw * 8;

    float dd[10], uu[10];
    {
        float t0[10], t1[10], t2[10];
        bool border = (cw == 0) | (cw == 63) | (ch == 0) | (ch == 63);
        if (__any((int)border)) {
            LOADROW_P(t0, row - 1)
            LOADROW_P(t1, row)
            LOADROW_P(t2, row + 1)
        } else {
            LOADROW_F(t0, row - 1)
            LOADROW_F(t1, row)
            LOADROW_F(t2, row + 1)
        }
#pragma unroll
        for (int c = 0; c < 10; ++c) {
            dd[c] = fmaf(2.0f, t1[c], t0[c] + t2[c]);
            uu[c] = t0[c] - t2[c];
        }
    }

    float gx[8], gy[8];
#pragma unroll
    for (int c = 0; c < 8; ++c) gx[c] = dd[c] - dd[c + 2];
#pragma unroll
    for (int c = 0; c < 8; ++c) gy[c] = fmaf(2.0f, uu[c + 1], uu[c] + uu[c + 2]);

    float cmagF[10];
#pragma unroll
    for (int b = 0; b < 10; ++b) cmagF[b] = 0.0f;
    unsigned long long pk = 0ull;   // 10 x 4-bit per-bin pixel counts (<=8)

#pragma unroll
    for (int c = 0; c < 8; ++c) {
        float gxc = gx[c], gyc = gy[c];
        float mag = __builtin_amdgcn_sqrtf(fmaf(gxc, gxc, gyc * gyc));
        float a = fabsf(gxc), b = fabsf(gyc);

        float m1 = fmaf(a, 0.95105651629515353f, -(b * 0.30901699437494740f));
        float m2 = fmaf(a, 0.80901699437494745f, -(b * 0.58778525229247314f));
        float m3 = fmaf(a, 0.58778525229247314f, -(b * 0.80901699437494745f));
        float m4 = fmaf(a, 0.30901699437494740f, -(b * 0.95105651629515353f));
        int neg = (int)(__float_as_uint(m1) >> 31) + (int)(__float_as_uint(m2) >> 31)
                + (int)(__float_as_uint(m3) >> 31) + (int)(__float_as_uint(m4) >> 31);
        bool qq = (((__float_as_uint(gxc) ^ __float_as_uint(gyc)) >> 31) != 0u);
        int fl = qq ? (5 + neg) : (4 - neg);

        float dmin = fminf(fminf(fminf(fabsf(m1), fabsf(m2)),
                                 fminf(fabsf(m3), fabsf(m4))),
                           fminf(a, b));
        if (dmin < THR_BASE * fmaxf(mag, 1.0f)) {
            // Rare: record for the fixup kernel (fast result still applied).
            unsigned idx = atomicAdd(cnt, 1u);
            unsigned pr = ((unsigned)n << 18) | ((unsigned)row << 9)
                        | (unsigned)(col0 + c);
            if (idx < cap) rec[idx] = pr;
        }

#pragma unroll
        for (int bb = 0; bb < 10; ++bb)
            cmagF[bb] += (bb == fl) ? mag : 0.0f;
        pk += 1ull << (fl * 4);
    }

    // bins[b] = cmag[b] - cmag[b-1] + cnt[b-1]; 8-lane shuffle butterfly
    float* op = out + (((size_t)n * 10) * 64 + ch) * 64 + cw;
#pragma unroll
    for (int b = 0; b < 10; ++b) {
        int bm1 = (b + 9) % 10;
        float c10 = (float)(unsigned)((pk >> (bm1 * 4)) & 15ull);
        float v = (cmagF[b] - cmagF[bm1]) + c10;
        v += __shfl_xor(v, 1);
        v += __shfl_xor(v, 2);
        v += __shfl_xor(v, 4);
        if (r == 0) op[(size_t)b * 4096] = v * (1.0f / 64.0f);
    }
}

// ---------------- Kernel B: rare boundary fixup (f64 lives here) ----------------
__global__ void __launch_bounds__(256) hog_fixup(const float* __restrict__ x,
                                                 float* __restrict__ out,
                                                 const unsigned* __restrict__ cnt,
                                                 const unsigned* __restrict__ rec,
                                                 unsigned cap) {
    unsigned total = *cnt;
    if (total > cap) total = cap;
    for (unsigned i = blockIdx.x * blockDim.x + threadIdx.x; i < total;
         i += gridDim.x * blockDim.x) {
        unsigned pr = rec[i];
        int pc  = (int)(pr & 511u);
        int row = (int)((pr >> 9) & 511u);
        int n   = (int)(pr >> 18);
        const float* img = x + (size_t)n * (512 * 512);

        int rm = row - 1, rq = row + 1;
        int cm = pc - 1, cp = pc + 1;
        bool rmok = rm >= 0, rqok = rq < 512;
        bool cmok = cm >= 0, cpok = cp < 512;
        float w00 = (rmok && cmok) ? img[(size_t)rm * 512 + cm] : 0.0f;
        float w01 = rmok ? img[(size_t)rm * 512 + pc] : 0.0f;
        float w02 = (rmok && cpok) ? img[(size_t)rm * 512 + cp] : 0.0f;
        float w10 = cmok ? img[(size_t)row * 512 + cm] : 0.0f;
        float w12 = cpok ? img[(size_t)row * 512 + cp] : 0.0f;
        float w20 = (rqok && cmok) ? img[(size_t)rq * 512 + cm] : 0.0f;
        float w21 = rqok ? img[(size_t)rq * 512 + pc] : 0.0f;
        float w22 = (rqok && cpok) ? img[(size_t)rq * 512 + cp] : 0.0f;

        // Bit-exact replication of kernel A's fast path (r7/r8-proven forms)
        float gxf = fmaf(2.0f, w10, w00 + w20) - fmaf(2.0f, w12, w02 + w22);
        float gyf = fmaf(2.0f, w01 - w21, (w00 - w20) + (w02 - w22));
        float magf = __builtin_amdgcn_sqrtf(fmaf(gxf, gxf, gyf * gyf));
        int negf = (int)(__float_as_uint(fmaf(fabsf(gxf), 0.95105651629515353f, -(fabsf(gyf) * 0.30901699437494740f))) >> 31)
                 + (int)(__float_as_uint(fmaf(fabsf(gxf), 0.80901699437494745f, -(fabsf(gyf) * 0.58778525229247314f))) >> 31)
                 + (int)(__float_as_uint(fmaf(fabsf(gxf), 0.58778525229247314f, -(fabsf(gyf) * 0.80901699437494745f))) >> 31)
                 + (int)(__float_as_uint(fmaf(fabsf(gxf), 0.30901699437494740f, -(fabsf(gyf) * 0.95105651629515353f))) >> 31);
        bool qqf = (((__float_as_uint(gxf) ^ __float_as_uint(gyf)) >> 31) != 0u);
        int flf = qqf ? (5 + negf) : (4 - negf);

        // Exact f64 sector classification (no atan2)
        double gxd = (((((double)w00 - (double)w02) + 2.0 * (double)w10)
                       - 2.0 * (double)w12) + (double)w20) - (double)w22;
        double gyd = (((((double)w00 + 2.0 * (double)w01) + (double)w02)
                       - (double)w20) - 2.0 * (double)w21) - (double)w22;
        int fls;
        float mvals;
        if (gxd == 0.0) { fls = 0; mvals = 1.0f; }        // p = 0 / +-10
        else if (gyd == 0.0) { fls = 5; mvals = 1.0f; }   // p = +-5
        else {
            double ad = fabs(gxd), bd = fabs(gyd);
            double M1 = fma(ad, 0.95105651629515353118, -(bd * 0.30901699437494742410));
            double M2 = fma(ad, 0.80901699437494742410, -(bd * 0.58778525229247312917));
            double M3 = fma(ad, 0.58778525229247312917, -(bd * 0.80901699437494742410));
            double M4 = fma(ad, 0.30901699437494742410, -(bd * 0.95105651629515353118));
            int negd = (int)(M1 < 0.0) + (int)(M2 < 0.0)
                     + (int)(M3 < 0.0) + (int)(M4 < 0.0);
            bool qd = (gxd < 0.0) != (gyd < 0.0);
            fls = qd ? (5 + negd) : (4 - negd);
            mvals = magf;
        }

        int ch = row >> 3, cw = pc >> 3;
        float* op = out + (((size_t)n * 10) * 64 + ch) * 64 + cw;
        int flf1 = (flf == 9) ? 0 : flf + 1;
        int fls1 = (fls == 9) ? 0 : fls + 1;
        // Undo fast contribution: bins[flf] += magf, bins[flf+1] += 1-magf
        atomicAdd(&op[(size_t)flf  * 4096], -magf * (1.0f / 64.0f));
        atomicAdd(&op[(size_t)flf1 * 4096], -(1.0f - magf) * (1.0f / 64.0f));
        // Apply exact contribution (mvals=1 encodes the fl==ce axis case)
        atomicAdd(&op[(size_t)fls  * 4096], mvals * (1.0f / 64.0f));
        atomicAdd(&op[(size_t)fls1 * 4096], (1.0f - mvals) * (1.0f / 64.0f));
    }
}

extern "C" void kernel_launch(void* const* d_in, const int* in_sizes, int n_in,
                              void* d_out, int out_size, void* d_ws, size_t ws_size,
                              hipStream_t stream) {
    const float* x = (const float*)d_in[0];
    float* out = (float*)d_out;
    unsigned* cnt = (unsigned*)d_ws;
    unsigned* rec = (unsigned*)((char*)d_ws + 16);
    unsigned cap = (ws_size > 16) ? (unsigned)((ws_size - 16) / 4) : 0u;

    hipMemsetAsync(cnt, 0, 4, stream);
    const int total = 16 * 64 * 64 * 8;  // 524288 threads
    hog_main<<<total / 256, 256, 0, stream>>>(x, out, cnt, rec, cap);
    hog_fixup<<<32, 256, 0, stream>>>(x, out, cnt, rec, cap);
}

// Round 10
// 21.022 us; speedup vs baseline: 2.9780x; 2.9780x over previous
//
#include <hip/hip_runtime.h>
#include <math.h>

#define THR_BASE 9.42477e-5f  // sin(3e-4 * pi/10): proven margin (rounds 2-9)

// Predicated (border) halo row load
#define LOADROW_P(DST, RR)                                                \
    {                                                                     \
        int rr = (RR);                                                    \
        bool rok = (rr >= 0) && (rr < 512);                               \
        const float* rp = img + (size_t)(rok ? rr : row) * 512;           \
        const float4* rp4 = (const float4*)(rp + col0);                   \
        float4 v0 = rp4[0], v1 = rp4[1];                                  \
        float lf = rp[(cw > 0) ? (col0 - 1) : col0];                      \
        float rt = rp[(cw < 63) ? (col0 + 8) : col0];                     \
        float m = rok ? 1.0f : 0.0f;                                      \
        DST[0] = (cw > 0 && rok) ? lf : 0.0f;                             \
        DST[1] = v0.x * m; DST[2] = v0.y * m;                             \
        DST[3] = v0.z * m; DST[4] = v0.w * m;                             \
        DST[5] = v1.x * m; DST[6] = v1.y * m;                             \
        DST[7] = v1.z * m; DST[8] = v1.w * m;                             \
        DST[9] = (cw < 63 && rok) ? rt : 0.0f;                            \
    }

// Unpredicated (interior-wave) halo row load
#define LOADROW_F(DST, RR)                                                \
    {                                                                     \
        const float* rp = img + (size_t)(RR) * 512;                       \
        const float4* rp4 = (const float4*)(rp + col0);                   \
        float4 v0 = rp4[0], v1 = rp4[1];                                  \
        DST[0] = rp[col0 - 1];                                            \
        DST[1] = v0.x; DST[2] = v0.y; DST[3] = v0.z; DST[4] = v0.w;       \
        DST[5] = v1.x; DST[6] = v1.y; DST[7] = v1.z; DST[8] = v1.w;       \
        DST[9] = rp[col0 + 8];                                            \
    }

// x: (16,1,512,512) f32 ; out: (16,10,64,64) f32
// thread t -> (n, ch, cw, r): r = t & 7 (pixel row within 8x8 cell)
// Round-8 structure; __launch_bounds__(256,4) -> VGPR budget 128, no spills.
__global__ void __launch_bounds__(256, 4) hog_kernel(const float* __restrict__ x,
                                                     float* __restrict__ out) {
    int t    = blockIdx.x * 256 + threadIdx.x;
    int r    = t & 7;
    int cell = t >> 3;           // 0 .. 65535
    int cw   = cell & 63;
    int ch   = (cell >> 6) & 63;
    int n    = cell >> 12;

    const float* img = x + (size_t)n * (512 * 512);
    int row  = ch * 8 + r;
    int col0 = cw * 8;

    // ---- Phase 1: rows -> dd[] (column sums), uu[] (row diffs) ----
    float dd[10], uu[10];
    {
        float t0[10], t1[10], t2[10];
        bool border = (cw == 0) | (cw == 63) | (ch == 0) | (ch == 63);
        if (__any((int)border)) {
            LOADROW_P(t0, row - 1)
            LOADROW_P(t1, row)
            LOADROW_P(t2, row + 1)
        } else {
            LOADROW_F(t0, row - 1)
            LOADROW_F(t1, row)
            LOADROW_F(t2, row + 1)
        }
#pragma unroll
        for (int c = 0; c < 10; ++c) {
            dd[c] = fmaf(2.0f, t1[c], t0[c] + t2[c]);
            uu[c] = t0[c] - t2[c];
        }
    }   // t0/t1/t2 dead here

    // ---- Phase 2: all 8 gx, then all 8 gy (dd, uu die in turn) ----
    float gx[8], gy[8];
#pragma unroll
    for (int c = 0; c < 8; ++c) gx[c] = dd[c] - dd[c + 2];
#pragma unroll
    for (int c = 0; c < 8; ++c) gy[c] = fmaf(2.0f, uu[c + 1], uu[c] + uu[c + 2]);

    // ---- Phase 3: hot loop on gx/gy only (8 independent chains) ----
    float cmagF[10];
#pragma unroll
    for (int b = 0; b < 10; ++b) cmagF[b] = 0.0f;
    unsigned long long pk = 0ull;   // 10 x 4-bit per-bin pixel counts (<=8)
    unsigned bmask = 0u;            // boundary-pixel flags (rare)

#pragma unroll
    for (int c = 0; c < 8; ++c) {
        float gxc = gx[c], gyc = gy[c];
        float mag = __builtin_amdgcn_sqrtf(fmaf(gxc, gxc, gyc * gyc));
        float a = fabsf(gxc), b = fabsf(gyc);

        // Sector tests: m_k = a*cos(k*pi/10) - b*sin(k*pi/10), k=1..4
        float m1 = fmaf(a, 0.95105651629515353f, -(b * 0.30901699437494740f));
        float m2 = fmaf(a, 0.80901699437494745f, -(b * 0.58778525229247314f));
        float m3 = fmaf(a, 0.58778525229247314f, -(b * 0.80901699437494745f));
        float m4 = fmaf(a, 0.30901699437494740f, -(b * 0.95105651629515353f));
        int neg = (int)(__float_as_uint(m1) >> 31) + (int)(__float_as_uint(m2) >> 31)
                + (int)(__float_as_uint(m3) >> 31) + (int)(__float_as_uint(m4) >> 31);
        bool qq = (((__float_as_uint(gxc) ^ __float_as_uint(gyc)) >> 31) != 0u);
        int fl = qq ? (5 + neg) : (4 - neg);

        float dmin = fminf(fminf(fminf(fabsf(m1), fabsf(m2)),
                                 fminf(fabsf(m3), fabsf(m4))),
                           fminf(a, b));
        bmask = (dmin < THR_BASE * fmaxf(mag, 1.0f)) ? (bmask | (1u << c)) : bmask;

#pragma unroll
        for (int bb = 0; bb < 10; ++bb)
            cmagF[bb] += (bb == fl) ? mag : 0.0f;
        pk += 1ull << (fl * 4);
    }

    // ---- Rare fixup: undo fast contribution, apply exact f64 sector ----
    while (__any((int)(bmask != 0u))) {
        if (bmask) {
            int c = (int)__builtin_ctz(bmask);
            bmask &= bmask - 1u;
            int pc = col0 + c;
            int rm = row - 1, rq = row + 1;
            int cm = pc - 1, cp = pc + 1;
            bool rmok = rm >= 0, rqok = rq < 512;
            bool cmok = cm >= 0, cpok = cp < 512;
            float w00 = (rmok && cmok) ? img[(size_t)rm * 512 + cm] : 0.0f;
            float w01 = rmok ? img[(size_t)rm * 512 + pc] : 0.0f;
            float w02 = (rmok && cpok) ? img[(size_t)rm * 512 + cp] : 0.0f;
            float w10 = cmok ? img[(size_t)row * 512 + cm] : 0.0f;
            float w12 = cpok ? img[(size_t)row * 512 + cp] : 0.0f;
            float w20 = (rqok && cmok) ? img[(size_t)rq * 512 + cm] : 0.0f;
            float w21 = rqok ? img[(size_t)rq * 512 + pc] : 0.0f;
            float w22 = (rqok && cpok) ? img[(size_t)rq * 512 + cp] : 0.0f;

            // Bit-exact replication of the fast path (same ops, same values)
            float gxf = fmaf(2.0f, w10, w00 + w20) - fmaf(2.0f, w12, w02 + w22);
            float gyf = fmaf(2.0f, w01 - w21, (w00 - w20) + (w02 - w22));
            float magf = __builtin_amdgcn_sqrtf(fmaf(gxf, gxf, gyf * gyf));
            int negf = (int)(__float_as_uint(fmaf(fabsf(gxf), 0.95105651629515353f, -(fabsf(gyf) * 0.30901699437494740f))) >> 31)
                     + (int)(__float_as_uint(fmaf(fabsf(gxf), 0.80901699437494745f, -(fabsf(gyf) * 0.58778525229247314f))) >> 31)
                     + (int)(__float_as_uint(fmaf(fabsf(gxf), 0.58778525229247314f, -(fabsf(gyf) * 0.80901699437494745f))) >> 31)
                     + (int)(__float_as_uint(fmaf(fabsf(gxf), 0.30901699437494740f, -(fabsf(gyf) * 0.95105651629515353f))) >> 31);
            bool qqf = (((__float_as_uint(gxf) ^ __float_as_uint(gyf)) >> 31) != 0u);
            int flf = qqf ? (5 + negf) : (4 - negf);

            // Undo fast contribution
#pragma unroll
            for (int bb = 0; bb < 10; ++bb)
                cmagF[bb] -= (bb == flf) ? magf : 0.0f;
            pk -= 1ull << (flf * 4);

            // Exact f64 sector classification (no atan2).
            double gxd = (((((double)w00 - (double)w02) + 2.0 * (double)w10)
                           - 2.0 * (double)w12) + (double)w20) - (double)w22;
            double gyd = (((((double)w00 + 2.0 * (double)w01) + (double)w02)
                           - (double)w20) - 2.0 * (double)w21) - (double)w22;
            int fls;
            float mvals;
            if (gxd == 0.0) { fls = 0; mvals = 1.0f; }        // p = 0 / +-10
            else if (gyd == 0.0) { fls = 5; mvals = 1.0f; }   // p = +-5
            else {
                double ad = fabs(gxd), bd = fabs(gyd);
                double M1 = fma(ad, 0.95105651629515353118, -(bd * 0.30901699437494742410));
                double M2 = fma(ad, 0.80901699437494742410, -(bd * 0.58778525229247312917));
                double M3 = fma(ad, 0.58778525229247312917, -(bd * 0.80901699437494742410));
                double M4 = fma(ad, 0.30901699437494742410, -(bd * 0.95105651629515353118));
                int negd = (int)(M1 < 0.0) + (int)(M2 < 0.0)
                         + (int)(M3 < 0.0) + (int)(M4 < 0.0);
                bool qd = (gxd < 0.0) != (gyd < 0.0);
                fls = qd ? (5 + negd) : (4 - negd);
                mvals = magf;
            }
#pragma unroll
            for (int bb = 0; bb < 10; ++bb)
                cmagF[bb] += (bb == fls) ? mvals : 0.0f;
            pk += 1ull << (fls * 4);
        }
    }

    // bins[b] = cmag[b] - cmag[b-1] + cnt[b-1]; 8-lane shuffle butterfly
    float* op = out + (((size_t)n * 10) * 64 + ch) * 64 + cw;
#pragma unroll
    for (int b = 0; b < 10; ++b) {
        int bm1 = (b + 9) % 10;
        float cnt = (float)(unsigned)((pk >> (bm1 * 4)) & 15ull);
        float v = (cmagF[b] - cmagF[bm1]) + cnt;
        v += __shfl_xor(v, 1);
        v += __shfl_xor(v, 2);
        v += __shfl_xor(v, 4);
        if (r == 0) op[(size_t)b * 4096] = v * (1.0f / 64.0f);
    }
}

extern "C" void kernel_launch(void* const* d_in, const int* in_sizes, int n_in,
                              void* d_out, int out_size, void* d_ws, size_t ws_size,
                              hipStream_t stream) {
    const float* x = (const float*)d_in[0];
    float* out = (float*)d_out;
    const int total = 16 * 64 * 64 * 8;  // 524288 threads
    hog_kernel<<<total / 256, 256, 0, stream>>>(x, out);
}

// Round 11
// 18.614 us; speedup vs baseline: 3.3634x; 1.1294x over previous
//
#include <hip/hip_runtime.h>
#include <math.h>

#define THR_BASE 9.42477e-5f  // sin(3e-4 * pi/10): proven margin (rounds 2-10)
#define KFOLD 256.0f          // count-fold constant: cmag[fl] += mag + KFOLD
#define KFOLD_INV 0.00390625f // 1/256

// Predicated (border) halo row load
#define LOADROW_P(DST, RR)                                                \
    {                                                                     \
        int rr = (RR);                                                    \
        bool rok = (rr >= 0) && (rr < 512);                               \
        const float* rp = img + (size_t)(rok ? rr : row0) * 512;          \
        const float4* rp4 = (const float4*)(rp + col0);                   \
        float4 v0 = rp4[0], v1 = rp4[1];                                  \
        float lf = rp[(cw > 0) ? (col0 - 1) : col0];                      \
        float rt = rp[(cw < 63) ? (col0 + 8) : col0];                     \
        float m = rok ? 1.0f : 0.0f;                                      \
        DST[0] = (cw > 0 && rok) ? lf : 0.0f;                             \
        DST[1] = v0.x * m; DST[2] = v0.y * m;                             \
        DST[3] = v0.z * m; DST[4] = v0.w * m;                             \
        DST[5] = v1.x * m; DST[6] = v1.y * m;                             \
        DST[7] = v1.z * m; DST[8] = v1.w * m;                             \
        DST[9] = (cw < 63 && rok) ? rt : 0.0f;                            \
    }

// Unpredicated (interior-wave) halo row load
#define LOADROW_F(DST, RR)                                                \
    {                                                                     \
        const float* rp = img + (size_t)(RR) * 512;                       \
        const float4* rp4 = (const float4*)(rp + col0);                   \
        float4 v0 = rp4[0], v1 = rp4[1];                                  \
        DST[0] = rp[col0 - 1];                                            \
        DST[1] = v0.x; DST[2] = v0.y; DST[3] = v0.z; DST[4] = v0.w;       \
        DST[5] = v1.x; DST[6] = v1.y; DST[7] = v1.z; DST[8] = v1.w;       \
        DST[9] = rp[col0 + 8];                                            \
    }

// x: (16,1,512,512) f32 ; out: (16,10,64,64) f32
// thread t -> (n, ch, cw, r2): r2 = t & 3 selects a 2-row pair of the 8x8
// cell. 4 threads/cell, 16 px/thread. Count-folded bins (mag + 256), no pk.
__global__ void __launch_bounds__(256) hog_kernel(const float* __restrict__ x,
                                                  float* __restrict__ out) {
    int t    = blockIdx.x * 256 + threadIdx.x;
    int r2   = t & 3;            // row-pair within cell
    int cell = t >> 2;           // 0 .. 65535
    int cw   = cell & 63;
    int ch   = (cell >> 6) & 63;
    int n    = cell >> 12;

    const float* img = x + (size_t)n * (512 * 512);
    int row0 = ch * 8 + r2 * 2;  // first of this thread's 2 pixel rows
    int col0 = cw * 8;

    // ---- Phase 1: 4 halo rows -> dd (col sums) / uu (row diffs) per pixel row
    float dd0[10], dd1[10], uu0[10], uu1[10];
    {
        float t0[10], t1[10], t2[10], t3[10];
        bool border = (cw == 0) | (cw == 63)
                    | ((ch == 0) & (r2 == 0)) | ((ch == 63) & (r2 == 3));
        if (__any((int)border)) {
            LOADROW_P(t0, row0 - 1)
            LOADROW_P(t1, row0)
            LOADROW_P(t2, row0 + 1)
            LOADROW_P(t3, row0 + 2)
        } else {
            LOADROW_F(t0, row0 - 1)
            LOADROW_F(t1, row0)
            LOADROW_F(t2, row0 + 1)
            LOADROW_F(t3, row0 + 2)
        }
#pragma unroll
        for (int c = 0; c < 10; ++c) {
            dd0[c] = fmaf(2.0f, t1[c], t0[c] + t2[c]);  // pixel row row0
            dd1[c] = fmaf(2.0f, t2[c], t1[c] + t3[c]);  // pixel row row0+1
            uu0[c] = t0[c] - t2[c];
            uu1[c] = t1[c] - t3[c];
        }
    }   // t0..t3 dead here

    // ---- Phase 2: all 16 gx / gy ----
    float gx[16], gy[16];
#pragma unroll
    for (int c = 0; c < 8; ++c) {
        gx[c]     = dd0[c] - dd0[c + 2];
        gx[8 + c] = dd1[c] - dd1[c + 2];
        gy[c]     = fmaf(2.0f, uu0[c + 1], uu0[c] + uu0[c + 2]);
        gy[8 + c] = fmaf(2.0f, uu1[c + 1], uu1[c] + uu1[c + 2]);
    }

    // ---- Phase 3: hot loop over 16 pixels ----
    float cmagF[10];
#pragma unroll
    for (int b = 0; b < 10; ++b) cmagF[b] = 0.0f;
    unsigned bmask = 0u;            // boundary-pixel flags (rare), 16 bits

#pragma unroll
    for (int p = 0; p < 16; ++p) {
        float gxc = gx[p], gyc = gy[p];
        float mag = __builtin_amdgcn_sqrtf(fmaf(gxc, gxc, gyc * gyc));
        float a = fabsf(gxc), b = fabsf(gyc);

        // Sector tests: m_k = a*cos(k*pi/10) - b*sin(k*pi/10), k=1..4
        float m1 = fmaf(a, 0.95105651629515353f, -(b * 0.30901699437494740f));
        float m2 = fmaf(a, 0.80901699437494745f, -(b * 0.58778525229247314f));
        float m3 = fmaf(a, 0.58778525229247314f, -(b * 0.80901699437494745f));
        float m4 = fmaf(a, 0.30901699437494740f, -(b * 0.95105651629515353f));
        int neg = (int)(__float_as_uint(m1) >> 31) + (int)(__float_as_uint(m2) >> 31)
                + (int)(__float_as_uint(m3) >> 31) + (int)(__float_as_uint(m4) >> 31);
        bool qq = (((__float_as_uint(gxc) ^ __float_as_uint(gyc)) >> 31) != 0u);
        int fl = qq ? (5 + neg) : (4 - neg);

        float dmin = fminf(fminf(fminf(fabsf(m1), fabsf(m2)),
                                 fminf(fabsf(m3), fabsf(m4))),
                           fminf(a, b));
        bmask = (dmin < THR_BASE * fmaxf(mag, 1.0f)) ? (bmask | (1u << p)) : bmask;

        float magK = mag + KFOLD;   // fold pixel-count into the accumulator
#pragma unroll
        for (int bb = 0; bb < 10; ++bb)
            cmagF[bb] += (bb == fl) ? magK : 0.0f;
    }

    // ---- Rare fixup: undo fast contribution, apply exact f64 sector ----
    while (__any((int)(bmask != 0u))) {
        if (bmask) {
            int p = (int)__builtin_ctz(bmask);
            bmask &= bmask - 1u;
            int prow = row0 + (p >> 3);
            int pc   = col0 + (p & 7);
            int rm = prow - 1, rq = prow + 1;
            int cm = pc - 1, cp = pc + 1;
            bool rmok = rm >= 0, rqok = rq < 512;
            bool cmok = cm >= 0, cpok = cp < 512;
            float w00 = (rmok && cmok) ? img[(size_t)rm * 512 + cm] : 0.0f;
            float w01 = rmok ? img[(size_t)rm * 512 + pc] : 0.0f;
            float w02 = (rmok && cpok) ? img[(size_t)rm * 512 + cp] : 0.0f;
            float w10 = cmok ? img[(size_t)prow * 512 + cm] : 0.0f;
            float w12 = cpok ? img[(size_t)prow * 512 + cp] : 0.0f;
            float w20 = (rqok && cmok) ? img[(size_t)rq * 512 + cm] : 0.0f;
            float w21 = rqok ? img[(size_t)rq * 512 + pc] : 0.0f;
            float w22 = (rqok && cpok) ? img[(size_t)rq * 512 + cp] : 0.0f;

            // Bit-exact replication of the fast path (same op forms/values)
            float gxf = fmaf(2.0f, w10, w00 + w20) - fmaf(2.0f, w12, w02 + w22);
            float gyf = fmaf(2.0f, w01 - w21, (w00 - w20) + (w02 - w22));
            float magf = __builtin_amdgcn_sqrtf(fmaf(gxf, gxf, gyf * gyf));
            int negf = (int)(__float_as_uint(fmaf(fabsf(gxf), 0.95105651629515353f, -(fabsf(gyf) * 0.30901699437494740f))) >> 31)
                     + (int)(__float_as_uint(fmaf(fabsf(gxf), 0.80901699437494745f, -(fabsf(gyf) * 0.58778525229247314f))) >> 31)
                     + (int)(__float_as_uint(fmaf(fabsf(gxf), 0.58778525229247314f, -(fabsf(gyf) * 0.80901699437494745f))) >> 31)
                     + (int)(__float_as_uint(fmaf(fabsf(gxf), 0.30901699437494740f, -(fabsf(gyf) * 0.95105651629515353f))) >> 31);
            bool qqf = (((__float_as_uint(gxf) ^ __float_as_uint(gyf)) >> 31) != 0u);
            int flf = qqf ? (5 + negf) : (4 - negf);

            // Undo fast contribution (magnitude + folded count)
            float undoK = magf + KFOLD;
#pragma unroll
            for (int bb = 0; bb < 10; ++bb)
                cmagF[bb] -= (bb == flf) ? undoK : 0.0f;

            // Exact f64 sector classification (no atan2).
            double gxd = (((((double)w00 - (double)w02) + 2.0 * (double)w10)
                           - 2.0 * (double)w12) + (double)w20) - (double)w22;
            double gyd = (((((double)w00 + 2.0 * (double)w01) + (double)w02)
                           - (double)w20) - 2.0 * (double)w21) - (double)w22;
            int fls;
            float mvals;
            if (gxd == 0.0) { fls = 0; mvals = 1.0f; }        // p = 0 / +-10
            else if (gyd == 0.0) { fls = 5; mvals = 1.0f; }   // p = +-5
            else {
                double ad = fabs(gxd), bd = fabs(gyd);
                double M1 = fma(ad, 0.95105651629515353118, -(bd * 0.30901699437494742410));
                double M2 = fma(ad, 0.80901699437494742410, -(bd * 0.58778525229247312917));
                double M3 = fma(ad, 0.58778525229247312917, -(bd * 0.80901699437494742410));
                double M4 = fma(ad, 0.30901699437494742410, -(bd * 0.95105651629515353118));
                int negd = (int)(M1 < 0.0) + (int)(M2 < 0.0)
                         + (int)(M3 < 0.0) + (int)(M4 < 0.0);
                bool qd = (gxd < 0.0) != (gyd < 0.0);
                fls = qd ? (5 + negd) : (4 - negd);
                mvals = magf;
            }
            float applyK = mvals + KFOLD;
#pragma unroll
            for (int bb = 0; bb < 10; ++bb)
                cmagF[bb] += (bb == fls) ? applyK : 0.0f;
        }
    }

    // ---- Tail: unfold counts, combine, 4-lane shuffle reduce, store ----
    // Per thread: n_b = rint(cmag/256), smag_b = cmag - 256*n_b.
    // bins[b] = smag[b] - smag[b-1] + n[b-1]; then sum across the 4
    // row-pair lanes of the cell (xor1 + xor2).
    float sm[10], nb[10];
#pragma unroll
    for (int b = 0; b < 10; ++b) {
        float q = rintf(cmagF[b] * KFOLD_INV);
        sm[b] = fmaf(q, -KFOLD, cmagF[b]);
        nb[b] = q;
    }
    float* op = out + (((size_t)n * 10) * 64 + ch) * 64 + cw;
#pragma unroll
    for (int b = 0; b < 10; ++b) {
        int bm1 = (b + 9) % 10;
        float v = (sm[b] - sm[bm1]) + nb[bm1];
        v += __shfl_xor(v, 1);
        v += __shfl_xor(v, 2);
        if (r2 == 0) op[(size_t)b * 4096] = v * (1.0f / 64.0f);
    }
}

extern "C" void kernel_launch(void* const* d_in, const int* in_sizes, int n_in,
                              void* d_out, int out_size, void* d_ws, size_t ws_size,
                              hipStream_t stream) {
    const float* x = (const float*)d_in[0];
    float* out = (float*)d_out;
    const int total = 16 * 64 * 64 * 4;  // 262144 threads, 16 px each
    hog_kernel<<<total / 256, 256, 0, stream>>>(x, out);
}